// Round 11
// baseline (112.484 us; speedup 1.0000x reference)
//
#include <hip/hip_runtime.h>
#include <float.h>
#include <math.h>

#define NSAMPLE 8192
#define KSEL 9          // K+1: keep 9 smallest incl. self
#define KNN 8
#define BLK 512
#define EPS_F 1e-12f

#define ROWS_PB 8                    // rows per block -> 1024 blocks
#define NBLOCKS (NSAMPLE / ROWS_PB)  // 1024
#define RPT 8                        // all 8 rows per thread (octant scan)
#define LANES 64
#define KQT 16                       // scan iters per wave (1024-cand octant / 64)
#define CHUNK 128                    // staged cands per chunk (2 per lane)
#define NCHUNK (1024 / CHUNK)        // 8
#define BNDI 4                       // bound iters per wave (256 of the octant)
#define WCAP 28                      // survivor cap per (wave,row) list (lambda~4.5)
#define IDX_MASK 0x1FFFu             // low 13 bits = candidate index
#define VAL_MASK 0xFFFFE000u         // high 19 bits = d2 (sign+exp+10 mantissa)
#define PSEL 76                      // select-scratch row stride (72 used + 4 pad;
                                     //   76*4 = 304 B, multiple of 16 -> uint4 ok)
#define SCALE (1.0f / (float)(NSAMPLE * KNN * 3))

// ---- LDS union layout (bytes). bpart (bound phase) and partS (select
// phase) overlay the staging buffer: bpart dies at the radix barrier before
// the first staging byte lands; partS is written only after the scan-end
// barrier (which drains the staging DMA). Total 40512 B -> 4 blocks/CU.
//   [0,     32768)  staging float4 [8 waves][2 bufs][128]   (scan)
//   [0,      4096)  bpart u32 [8 rows][128]                 (bound)
//   [0,      2432)  partS u32 [8 rows][PSEL=76]             (select)
//   [32768, 39936)  wl    u32 [64 lists * 28]               (scan + select)
//   [39936, 40192)  wcnt  u32 [64]
//   [40192, 40224)  bnd   u32 [8]
//   [40224, 40256)  red   f32 [8]
//   [40256, 40512)  tarr  f32 [8 rows][8 ranks]
#define OFF_WL      32768
#define OFF_WCNT    (OFF_WL + 64 * WCAP * 4)      // 39936
#define OFF_BND     (OFF_WCNT + 256)              // 40192
#define OFF_RED     (OFF_BND + 32)                // 40224
#define OFF_TARR    (OFF_RED + 32)                // 40256
#define SMEM_BYTES  (OFF_TARR + 256)              // 40512

__device__ __forceinline__ unsigned umn(unsigned a, unsigned b) { return a < b ? a : b; }
__device__ __forceinline__ unsigned umx(unsigned a, unsigned b) { return a > b ? a : b; }

// Branchless insert of x into descending-sorted s[0..8] (s[0]=worst, s[8]=best).
__device__ __forceinline__ void insert9(unsigned s[KSEL], unsigned x)
{
#pragma unroll
    for (int k = 0; k < KSEL - 1; ++k)
        s[k] = umx(s[k + 1], umn(x, s[k]));
    s[KSEL - 1] = umn(x, s[KSEL - 1]);
}

// Packed (d2 | idx). d2 clamped >= 0 so self packs minimal.
__device__ __forceinline__ unsigned pack_d2(float d2, int gidx)
{
    return (__float_as_uint(fmaxf(d2, 0.0f)) & VAL_MASK) | (unsigned)gidx;
}

// Force a wave-uniform float into an SGPR (frees per-lane VGPR copies).
__device__ __forceinline__ float sfl(float x)
{
    return __uint_as_float((unsigned)__builtin_amdgcn_readfirstlane(
        (int)__float_as_uint(x)));
}

// popcount(mask & lanes_below_me) in 2 VALU (v_mbcnt_lo/hi).
__device__ __forceinline__ unsigned mbcnt64(unsigned long long m)
{
    return __builtin_amdgcn_mbcnt_hi((unsigned)(m >> 32),
           __builtin_amdgcn_mbcnt_lo((unsigned)(m & 0xFFFFFFFFull), 0u));
}

// Direct global->LDS DMA (gfx950): per-lane global src, wave-uniform LDS
// base; HW writes lane i's 16B at base + i*16. No VGPR destination =>
// regalloc cannot spill or sink it (the R20-R22 failure modes).
__device__ __forceinline__ void load_lds16(const float4* g, float4* l)
{
    __builtin_amdgcn_global_load_lds(
        (const __attribute__((address_space(1))) void*)g,
        (__attribute__((address_space(3))) void*)l, 16, 0, 0);
}

// ---------------------------------------------------------------------------
// Kernel 1: one-time gather into compact L2-resident float4 arrays:
//   sm4 = (mean.xyz, |mean|^2), ss4 = (sh0.xyz, 0).
// ---------------------------------------------------------------------------
__global__ __launch_bounds__(256) void gather_k(
    const float* __restrict__ means, const float* __restrict__ sh0,
    const int* __restrict__ idx,
    float4* __restrict__ sm4, float4* __restrict__ ss4)
{
    int i = blockIdx.x * 256 + threadIdx.x;
    if (i >= NSAMPLE) return;
    int id = idx[i];
    const float* m = means + 3 * id;
    const float* s = sh0 + 3 * id;
    float mx = m[0], my = m[1], mz = m[2];
    sm4[i] = make_float4(mx, my, mz, fmaf(mx, mx, fmaf(my, my, mz * mz)));
    ss4[i] = make_float4(s[0], s[1], s[2], 0.0f);
}

// ---------------------------------------------------------------------------
// Kernel 2 (R27): R26's two parallelized selection structures with the
// select-phase geometry bug fixed. R26 post-mortem: PSEL=40 ("36 values/
// row") was a fossil of the old 4-quarter layout -- Select A writes 8 waves
// x 9 = 72 values/row (offsets to r1*stride+71), so rows overran each other
// and Select B ranked over half the corrupted merge. absmax 0.578. Fix:
//   - PSEL 40 -> 76 (72 + 4 pad; row base stays 16B-aligned).
//   - Select B covers all 72 values/row: wave w owns row w; lane l ranks
//     value l, lanes 0..7 also values 64..71 (18 broadcast uint4 reads).
//     Uniqueness: real values carry distinct candidate idx; sentinels rank
//     >= 9 (>= 9 reals survive). Ranks 1..8 -> one epilogue thread each;
//     tarr zero-inited; ordered sum rank 8->1, rows 0->7 as before.
// Radix-select bound (verified bit-exact vs the old ladder: the 9th packed
// value's 19 value-bits == 9th of the value-bit multiset, and the screen
// only consumes bnd|IDX_MASK), scan loop, staging, WCAP, geometry: all
// bit-inherited from R25/R26.
// Tripwires: FETCH ~1.2MB / WRITE 32KB / VGPR <=48 / LDS ~40.5KB.
// ---------------------------------------------------------------------------
// Process rows R..R+3 (R = literal 0 or 4) of one candidate register Q.
#define QUAD(R, Q, CI)                                                        \
    {                                                                         \
        float v0 = fmaf(cX[(R) + 0], (Q).x, fmaf(cY[(R) + 0], (Q).y,          \
                   fmaf(cZ[(R) + 0], (Q).z, (Q).w)));                         \
        float v1 = fmaf(cX[(R) + 1], (Q).x, fmaf(cY[(R) + 1], (Q).y,          \
                   fmaf(cZ[(R) + 1], (Q).z, (Q).w)));                         \
        float v2 = fmaf(cX[(R) + 2], (Q).x, fmaf(cY[(R) + 2], (Q).y,          \
                   fmaf(cZ[(R) + 2], (Q).z, (Q).w)));                         \
        float v3 = fmaf(cX[(R) + 3], (Q).x, fmaf(cY[(R) + 3], (Q).y,          \
                   fmaf(cZ[(R) + 3], (Q).z, (Q).w)));                         \
        unsigned long long m0 = __ballot(v0 <= sb[(R) + 0]);                  \
        unsigned long long m1 = __ballot(v1 <= sb[(R) + 1]);                  \
        unsigned long long m2 = __ballot(v2 <= sb[(R) + 2]);                  \
        unsigned long long m3 = __ballot(v3 <= sb[(R) + 3]);                  \
        if (m0) {                                                             \
            unsigned pos = base[(R) + 0] + mbcnt64(m0);                       \
            if ((v0 <= sb[(R) + 0]) && pos < WCAP)                            \
                wl[(w * RPT + (R) + 0) * WCAP + pos] =                        \
                    pack_d2(v0 + cW[(R) + 0], (CI));                          \
            base[(R) + 0] += (unsigned)__popcll(m0);                          \
        }                                                                     \
        if (m1) {                                                             \
            unsigned pos = base[(R) + 1] + mbcnt64(m1);                       \
            if ((v1 <= sb[(R) + 1]) && pos < WCAP)                            \
                wl[(w * RPT + (R) + 1) * WCAP + pos] =                        \
                    pack_d2(v1 + cW[(R) + 1], (CI));                          \
            base[(R) + 1] += (unsigned)__popcll(m1);                          \
        }                                                                     \
        if (m2) {                                                             \
            unsigned pos = base[(R) + 2] + mbcnt64(m2);                       \
            if ((v2 <= sb[(R) + 2]) && pos < WCAP)                            \
                wl[(w * RPT + (R) + 2) * WCAP + pos] =                        \
                    pack_d2(v2 + cW[(R) + 2], (CI));                          \
            base[(R) + 2] += (unsigned)__popcll(m2);                          \
        }                                                                     \
        if (m3) {                                                             \
            unsigned pos = base[(R) + 3] + mbcnt64(m3);                       \
            if ((v3 <= sb[(R) + 3]) && pos < WCAP)                            \
                wl[(w * RPT + (R) + 3) * WCAP + pos] =                        \
                    pack_d2(v3 + cW[(R) + 3], (CI));                          \
            base[(R) + 3] += (unsigned)__popcll(m3);                          \
        }                                                                     \
    }

__global__ __launch_bounds__(BLK, 8) void main_k(
    const float4* __restrict__ sm4, const float4* __restrict__ ss4,
    float* __restrict__ partial)
{
    __shared__ __align__(16) unsigned char smem[SMEM_BYTES];
    float4*   stg   = (float4*)smem;                      // scan staging
    unsigned* bpart = (unsigned*)smem;                    // bound (dead later)
    unsigned* partS = (unsigned*)smem;                    // select (after scan)
    unsigned* wl    = (unsigned*)(smem + OFF_WL);
    unsigned* wcnt  = (unsigned*)(smem + OFF_WCNT);
    unsigned* bnd   = (unsigned*)(smem + OFF_BND);
    float*    red   = (float*)(smem + OFF_RED);
    float*    tarr  = (float*)(smem + OFF_TARR);

    const int t = threadIdx.x;
    const int lane = t & (LANES - 1);
    const int w = t >> 6;                       // 0..7 (wave id = octant)

    // Own-row coefficients -> SGPRs (wave-uniform; canonical d2 = s + cW
    // where s = fmaf(cX,qx, fmaf(cY,qy, fmaf(cZ,qz, qw)))).
    float cX[RPT], cY[RPT], cZ[RPT], cW[RPT];
#pragma unroll
    for (int i = 0; i < RPT; ++i) {
        float4 p = sm4[blockIdx.x * ROWS_PB + i];
        cX[i] = sfl(-2.0f * p.x);
        cY[i] = sfl(-2.0f * p.y);
        cZ[i] = sfl(-2.0f * p.z);
        cW[i] = sfl(p.w);
    }

    // ---- Bound: per-lane packed min over 4-cand slices of the octant's
    // first 256 cands (8 octants -> 2048-cand sample). Fold lanes ^32,^16
    // -> 128 minima/row (each the min of 16 distinct candidates).
    {
        unsigned pm[RPT];
#pragma unroll
        for (int i = 0; i < RPT; ++i) pm[i] = 0xFFFFFFFFu;
        const int b0 = w * (KQT * LANES);
        const float4* __restrict__ bp = sm4 + b0 + lane;
#pragma unroll
        for (int k = 0; k < BNDI; ++k) {
            const int ci = b0 + k * LANES + lane;
            float4 q = bp[k * LANES];
#pragma unroll
            for (int i = 0; i < RPT; ++i) {
                float s = fmaf(cX[i], q.x,
                          fmaf(cY[i], q.y, fmaf(cZ[i], q.z, q.w)));
                pm[i] = umn(pm[i], pack_d2(s + cW[i], ci));  // canonical d2
            }
        }
#pragma unroll
        for (int i = 0; i < RPT; ++i) {
            pm[i] = umn(pm[i], (unsigned)__shfl_xor((int)pm[i], 32, 64));
            pm[i] = umn(pm[i], (unsigned)__shfl_xor((int)pm[i], 16, 64));
        }
        if (lane < 16) {
#pragma unroll
            for (int i = 0; i < RPT; ++i)
                bpart[i * 128 + w * 16 + lane] = pm[i];
        }
    }
    __syncthreads();

    // ---- Radix-select: wave w finds the exact 19-bit value-prefix P of
    // the 9th smallest of row w's 128 minima (2 values/lane, in registers).
    // (P<<13)|IDX_MASK == old ladder's bnd|IDX_MASK bit-exactly.
    {
        const unsigned p0 = bpart[w * 128 + lane] >> 13;
        const unsigned p1 = bpart[w * 128 + 64 + lane] >> 13;
        unsigned P = 0;
#pragma unroll 1
        for (int b = 18; b >= 0; --b) {
            const unsigned x = P + (1u << b) - 1u;   // bit b=0, lower bits 1
            const unsigned cnt = (unsigned)__popcll(__ballot(p0 <= x))
                               + (unsigned)__popcll(__ballot(p1 <= x));
            if (cnt < 9u) P |= (1u << b);            // wave-uniform
        }
        if (lane == 0) bnd[w] = (P << 13);
    }
    __syncthreads();                            // bpart now dead

    // s-space screen bound: pack(d2)|idx <= b requires d2 <= bf where
    // bf = uint_as_float(b | IDX_MASK) (positive floats: uint order == float
    // order). d2 = fl(s + cW) <= bf  ==>  s <= (bf - cW) + ~ulp slack; the
    // relative loosening (on bf AND the difference) keeps sb a superset
    // bound under all cancellation cases. Extras are harmless.
    float sb[RPT];
#pragma unroll
    for (int i = 0; i < RPT; ++i) {
        float bfv = __uint_as_float(bnd[i] | IDX_MASK);
        float D = bfv - cW[i];
        sb[i] = sfl(D + (bfv + fabsf(D)) * 6.0e-7f + 1e-33f);
    }

    // ---- Scan: LDS-staged octant stream (R23/R25 loop verbatim) ----------
    unsigned base[RPT];
#pragma unroll
    for (int i = 0; i < RPT; ++i) base[i] = 0u;

    const int s0 = w * (KQT * LANES);
    const float4* __restrict__ gsrc = sm4 + s0;

    // Prologue: chunk 0 -> buf 0 (staging first touches LDS only after the
    // radix barrier above -- the bpart overlay is temporally safe).
    load_lds16(gsrc + lane,      stg + (w * 2 + 0) * CHUNK);
    load_lds16(gsrc + 64 + lane, stg + (w * 2 + 0) * CHUNK + 64);

#pragma unroll 1
    for (int c = 0; c < NCHUNK; ++c) {
        // Issue chunk c+1 into the other buffer. c=7 over-issues one chunk
        // (w=7 source lands in ss4 -- allocated, value never consumed) so
        // the body stays branch-free and vmcnt(2) is correct on every iter.
        const float4* gn = gsrc + (c + 1) * CHUNK;
        float4* ln = stg + (w * 2 + ((c + 1) & 1)) * CHUNK;
        load_lds16(gn + lane,      ln);
        load_lds16(gn + 64 + lane, ln + 64);

        // Chunk c's 2 loads retired (in-order) once <=2 remain outstanding.
        asm volatile("s_waitcnt vmcnt(2)" ::: "memory");
        __builtin_amdgcn_sched_barrier(0);

        const float4* buf = stg + (w * 2 + (c & 1)) * CHUNK;
        float4 q0 = buf[lane];
        float4 q1 = buf[64 + lane];
        const int ci0 = s0 + c * CHUNK + lane;
        QUAD(0, q0, ci0)
        QUAD(4, q0, ci0)
        QUAD(0, q1, ci0 + 64)
        QUAD(4, q1, ci0 + 64)
    }

    if (lane == 0) {
#pragma unroll
        for (int i = 0; i < RPT; ++i)
            wcnt[w * RPT + i] = umn(base[i], WCAP);
    }
    __syncthreads();                             // survivor lists complete
                                                 // (drains vmcnt; staging dead)

    // ---- Select A: 64 tasks (wave 0), each merges one (wave,row) list ----
    if (t < 64) {
        const int r1 = t & (ROWS_PB - 1);        // row
        const int wv = t >> 3;                   // 0..7 octant wave
        const int li = wv * RPT + r1;
        const unsigned n = wcnt[li];
        unsigned s[KSEL];
#pragma unroll
        for (int k = 0; k < KSEL; ++k) s[k] = 0xFFFFFFFFu;
        for (unsigned k = 0; k < n; ++k)
            insert9(s, wl[li * WCAP + k]);
#pragma unroll
        for (int k = 0; k < KSEL; ++k)
            partS[r1 * PSEL + wv * KSEL + k] = s[k];
    }
    if (t < 64) tarr[t] = 0.0f;                  // defensive zero-init
    __syncthreads();

    // ---- Select B: rank-count over all 72 values/row + PARALLEL epilogue.
    // Wave w owns row w: lane l ranks value l; lanes 0..7 also rank values
    // 64..71. Real values unique (distinct candidate idx); sentinels
    // (0xFFFFFFFF) rank >= 9 since >= 9 reals survive per row. rank 0 =
    // global min (self / zero-term dup) -> dropped; ranks 1..8 = the 8
    // neighbors, each handled by exactly ONE thread.
    {
        const int r1 = w;
        const unsigned vA = partS[r1 * PSEL + lane];
        const unsigned vB = (lane < 8) ? partS[r1 * PSEL + 64 + lane]
                                       : 0xFFFFFFFFu;
        unsigned rkA = 0, rkB = 0;
#pragma unroll
        for (int e = 0; e < 18; ++e) {           // 72 values = 18 uint4
            const uint4 u = *(const uint4*)&partS[r1 * PSEL + e * 4];
            rkA += (unsigned)(u.x < vA) + (unsigned)(u.y < vA)
                 + (unsigned)(u.z < vA) + (unsigned)(u.w < vA);
            rkB += (unsigned)(u.x < vB) + (unsigned)(u.y < vB)
                 + (unsigned)(u.z < vB) + (unsigned)(u.w < vB);
        }
        const int gr = blockIdx.x * ROWS_PB + r1;
        if (rkA >= 1u && rkA <= 8u) {
            const int j = (int)(vA & IDX_MASK);
            float4 pm4 = sm4[gr];
            float4 ps4 = ss4[gr];
            float4 qm = sm4[j];
            float dx = pm4.x - qm.x, dy = pm4.y - qm.y, dz = pm4.z - qm.z;
            float d2 = fmaf(dx, dx, fmaf(dy, dy, dz * dz));
            float d = sqrtf(fmaxf(d2, EPS_F));
            float wgt = expf(-d);
            float4 qs = ss4[j];
            float ax = ps4.x - qs.x, ay = ps4.y - qs.y, az = ps4.z - qs.z;
            tarr[r1 * 8 + (int)(rkA - 1u)] = wgt * (ax * ax + ay * ay + az * az);
        }
        if (lane < 8 && rkB >= 1u && rkB <= 8u) {
            const int j = (int)(vB & IDX_MASK);
            float4 pm4 = sm4[gr];
            float4 ps4 = ss4[gr];
            float4 qm = sm4[j];
            float dx = pm4.x - qm.x, dy = pm4.y - qm.y, dz = pm4.z - qm.z;
            float d2 = fmaf(dx, dx, fmaf(dy, dy, dz * dz));
            float d = sqrtf(fmaxf(d2, EPS_F));
            float wgt = expf(-d);
            float4 qs = ss4[j];
            float ax = ps4.x - qs.x, ay = ps4.y - qs.y, az = ps4.z - qs.z;
            tarr[r1 * 8 + (int)(rkB - 1u)] = wgt * (ax * ax + ay * ay + az * az);
        }
    }
    __syncthreads();

    if (t < ROWS_PB) {                          // ordered sum: rank 8 -> 1
        float acc = 0.0f;
#pragma unroll
        for (int k = 7; k >= 0; --k) acc += tarr[t * 8 + k];
        red[t] = acc;
    }
    __syncthreads();
    if (t == 0) {
        float ssum = 0.0f;
#pragma unroll
        for (int i = 0; i < ROWS_PB; ++i) ssum += red[i];
        partial[blockIdx.x] = ssum;              // plain store
    }
}

// ---------------------------------------------------------------------------
// Kernel 3: reduce 1024 block partials -> scalar (cost ~0, proven R15;
// kept deterministic/order-identical so the output stays stable).
// ---------------------------------------------------------------------------
__global__ __launch_bounds__(256) void reduce_k(
    const float* __restrict__ partial, float* __restrict__ out)
{
    __shared__ float sbuf[4];
    int t = threadIdx.x;
    float v = 0.0f;
    for (int i = t; i < NBLOCKS; i += 256) v += partial[i];
    for (int off = 32; off > 0; off >>= 1) v += __shfl_down(v, off);
    if ((t & 63) == 0) sbuf[t >> 6] = v;
    __syncthreads();
    if (t == 0) {
        float s = sbuf[0] + sbuf[1] + sbuf[2] + sbuf[3];
        out[0] = s * SCALE;
    }
}

// ---------------------------------------------------------------------------
extern "C" void kernel_launch(void* const* d_in, const int* in_sizes, int n_in,
                              void* d_out, int out_size, void* d_ws, size_t ws_size,
                              hipStream_t stream)
{
    const float* means = (const float*)d_in[0];
    const float* sh0   = (const float*)d_in[1];
    const int*   idxp  = (const int*)d_in[2];

    float4* sm4 = (float4*)d_ws;                 // 128 KB
    float4* ss4 = sm4 + NSAMPLE;                 // 128 KB
    float*  partial = (float*)(ss4 + NSAMPLE);   // 4 KB

    gather_k<<<NSAMPLE / 256, 256, 0, stream>>>(means, sh0, idxp, sm4, ss4);
    main_k<<<NBLOCKS, BLK, 0, stream>>>(sm4, ss4, partial);
    reduce_k<<<1, 256, 0, stream>>>(partial, (float*)d_out);
}